// Round 6
// baseline (2530.481 us; speedup 1.0000x reference)
//
#include <hip/hip_runtime.h>

typedef __bf16 bf16;
typedef __bf16 bf16x8 __attribute__((ext_vector_type(8)));
typedef float f32x4 __attribute__((ext_vector_type(4)));

#define NPIX 4096   // 64*64

// ---------------------------------------------------------------------------
// Pure-fp32 GEMM (VALU): C[m][n] = sum_k A[m][k]*B[k][n].  M=768, K=256.
// Branch-critical path: q/k enter relu + ratio; needs fp32-level accuracy.
// Block 256 = 64 n-lanes x 4 m-subblocks; each thread 32 m's. grid (64, 6).
// ---------------------------------------------------------------------------
__global__ __launch_bounds__(256) void gemm_f32(
    const float* __restrict__ A,  // [768][256]
    const float* __restrict__ B,  // [256][NPIX]
    float* __restrict__ C)        // [768][NPIX]
{
    const int n  = blockIdx.x * 64 + (threadIdx.x & 63);
    const int m0 = blockIdx.y * 128 + (threadIdx.x >> 6) * 32;

    float acc[32] = {};
    const float* __restrict__ Ab = A + (size_t)m0 * 256;

    for (int k = 0; k < 256; k += 2) {
        float b0 = B[(size_t)k * NPIX + n];
        float b1 = B[(size_t)(k + 1) * NPIX + n];
#pragma unroll
        for (int i = 0; i < 32; ++i) {
            acc[i] = fmaf(Ab[(size_t)i * 256 + k], b0, acc[i]);
            acc[i] = fmaf(Ab[(size_t)i * 256 + k + 1], b1, acc[i]);
        }
    }
#pragma unroll
    for (int i = 0; i < 32; ++i)
        C[(size_t)(m0 + i) * NPIX + n] = acc[i];
}

// ---------------------------------------------------------------------------
// Split-bf16 MFMA GEMM + BN epilogue (proj only: error propagates linearly).
// C[m][n] = BN( sum_k A[m][k]*B[k][n] ).  M=256, K=512. grid (64, 4).
// ---------------------------------------------------------------------------
__global__ __launch_bounds__(256) void gemm_bn(
    const float* __restrict__ A,  // [M][K] fp32
    const float* __restrict__ B,  // [K][NPIX] fp32
    float* __restrict__ C,        // [M][NPIX] fp32
    int M, int K,
    const float* __restrict__ bn_g, const float* __restrict__ bn_b,
    const float* __restrict__ bn_m, const float* __restrict__ bn_v)
{
    const int lane = threadIdx.x & 63;
    const int wv   = threadIdx.x >> 6;
    const int col  = lane & 15;
    const int quad = lane >> 4;
    const int n    = blockIdx.x * 64 + wv * 16 + col;
    const int m0   = blockIdx.y * 64;

    f32x4 acc[4] = {};

    for (int k0 = quad * 8; k0 < K; k0 += 32) {
        bf16x8 b_hi, b_lo;
        const float* bp = B + (size_t)k0 * NPIX + n;
#pragma unroll
        for (int j = 0; j < 8; ++j) {
            float bv = bp[(size_t)j * NPIX];
            b_hi[j] = (bf16)bv;
            b_lo[j] = (bf16)(bv - (float)b_hi[j]);
        }
#pragma unroll
        for (int s = 0; s < 4; ++s) {
            const float* ap = A + (size_t)(m0 + s * 16 + col) * K + k0;
            bf16x8 a_hi, a_lo;
#pragma unroll
            for (int j = 0; j < 8; ++j) {
                float av = ap[j];
                a_hi[j] = (bf16)av;
                a_lo[j] = (bf16)(av - (float)a_hi[j]);
            }
            acc[s] = __builtin_amdgcn_mfma_f32_16x16x32_bf16(a_lo, b_hi, acc[s], 0, 0, 0);
            acc[s] = __builtin_amdgcn_mfma_f32_16x16x32_bf16(a_hi, b_lo, acc[s], 0, 0, 0);
            acc[s] = __builtin_amdgcn_mfma_f32_16x16x32_bf16(a_hi, b_hi, acc[s], 0, 0, 0);
        }
    }

#pragma unroll
    for (int s = 0; s < 4; ++s) {
#pragma unroll
        for (int r = 0; r < 4; ++r) {
            int m = m0 + s * 16 + quad * 4 + r;
            float v = acc[s][r];
            float sc = (1.0f / sqrtf(bn_v[m] + 1e-5f)) * bn_g[m];
            v = v * sc + (bn_b[m] - bn_m[m] * sc);
            C[(size_t)m * NPIX + n] = v;
        }
    }
}

// ---------------------------------------------------------------------------
// Fused depthwise 5x5 (pad 2) + grouped pointwise 8->8, single batch, fp32.
// grid = (4, 4, 96); block = 256 (16x16 pixels)
// ---------------------------------------------------------------------------
__global__ __launch_bounds__(256) void dwpw(
    const float* __restrict__ qkv,   // [768][NPIX]
    const float* __restrict__ w_dw,  // [768][25]
    const float* __restrict__ w_pw,  // [768][8]
    float* __restrict__ agg)         // [768][NPIX]
{
    __shared__ float sm[8][20][20];
    __shared__ float wdw[8][25];
    __shared__ float wpw[8][8];

    const int tid = threadIdx.x;
    const int p   = blockIdx.z;
    const int y0  = blockIdx.y * 16;
    const int x0  = blockIdx.x * 16;

    const float* __restrict__ src = qkv + (size_t)(8 * p) * NPIX;

    for (int i = tid; i < 8 * 400; i += 256) {
        int c = i / 400, r = i % 400;
        int sy = r / 20, sx = r % 20;
        int gy = y0 + sy - 2, gx = x0 + sx - 2;
        float v = 0.0f;
        if ((unsigned)gy < 64u && (unsigned)gx < 64u)
            v = src[(size_t)c * NPIX + gy * 64 + gx];
        sm[c][sy][sx] = v;
    }
    if (tid < 200) {
        int c = tid / 25, t = tid % 25;
        wdw[c][t] = w_dw[(size_t)(8 * p + c) * 25 + t];
    }
    if (tid < 64) {
        int o = tid / 8, i = tid % 8;
        wpw[o][i] = w_pw[(size_t)(8 * p + o) * 8 + i];
    }
    __syncthreads();

    const int ty = tid >> 4, tx = tid & 15;

    float d[8];
#pragma unroll
    for (int c = 0; c < 8; ++c) {
        float s = 0.0f;
#pragma unroll
        for (int ky = 0; ky < 5; ++ky)
#pragma unroll
            for (int kx = 0; kx < 5; ++kx)
                s += wdw[c][ky * 5 + kx] * sm[c][ty + ky][tx + kx];
        d[c] = s;
    }

    float* __restrict__ dst = agg + (size_t)(8 * p) * NPIX + (y0 + ty) * 64 + (x0 + tx);
#pragma unroll
    for (int o = 0; o < 8; ++o) {
        float s = 0.0f;
#pragma unroll
        for (int i = 0; i < 8; ++i) s += wpw[o][i] * d[i];
        dst[(size_t)o * NPIX] = s;
    }
}

// ---------------------------------------------------------------------------
// kv[g][d][e] = sum_n relu(k[n][d]) * v'[n][e]   (v'[:,8] = 1)
// grid = (64); block = 256.  No atomics: one block per group.
// ---------------------------------------------------------------------------
__global__ __launch_bounds__(256) void kv_reduce(
    const float* __restrict__ qkv, const float* __restrict__ agg,
    float* __restrict__ kvb)      // [64][72]
{
    const int g = blockIdx.x;
    const float* __restrict__ src = (g < 32) ? qkv : agg;
    const float* __restrict__ base = src + (size_t)(24 * (g & 31)) * NPIX;

    float acc[72];
#pragma unroll
    for (int i = 0; i < 72; ++i) acc[i] = 0.0f;

    for (int n = threadIdx.x; n < NPIX; n += 256) {
        float kf[8], vf[8];
#pragma unroll
        for (int d = 0; d < 8; ++d) kf[d] = fmaxf(0.0f, base[(size_t)(8 + d) * NPIX + n]);
#pragma unroll
        for (int e = 0; e < 8; ++e) vf[e] = base[(size_t)(16 + e) * NPIX + n];
#pragma unroll
        for (int d = 0; d < 8; ++d) {
#pragma unroll
            for (int e = 0; e < 8; ++e) acc[d * 9 + e] += kf[d] * vf[e];
            acc[d * 9 + 8] += kf[d];
        }
    }

    const int lane = threadIdx.x & 63;
    const int wv   = threadIdx.x >> 6;
#pragma unroll
    for (int i = 0; i < 72; ++i) {
        float v = acc[i];
        v += __shfl_xor(v, 32, 64);
        v += __shfl_xor(v, 16, 64);
        v += __shfl_xor(v, 8, 64);
        v += __shfl_xor(v, 4, 64);
        v += __shfl_xor(v, 2, 64);
        v += __shfl_xor(v, 1, 64);
        acc[i] = v;
    }
    __shared__ float red[4][72];
    if (lane == 0) {
#pragma unroll
        for (int i = 0; i < 72; ++i) red[wv][i] = acc[i];
    }
    __syncthreads();
    if (threadIdx.x < 72)
        kvb[(size_t)g * 72 + threadIdx.x] =
            red[0][threadIdx.x] + red[1][threadIdx.x] +
            red[2][threadIdx.x] + red[3][threadIdx.x];
}

// ---------------------------------------------------------------------------
// att[g*8+e][n] = (sum_d relu(q[n][d]) kv[d][e]) / (sum_d relu(q[n][d]) kv[d][8] + eps)
// grid = (16, 64); block = 256
// ---------------------------------------------------------------------------
__global__ __launch_bounds__(256) void attn_apply(
    const float* __restrict__ qkv, const float* __restrict__ agg,
    const float* __restrict__ kvb,
    float* __restrict__ att)      // [512][NPIX]
{
    const int g = blockIdx.y;
    const int n = blockIdx.x * 256 + threadIdx.x;

    __shared__ float kvs[72];
    if (threadIdx.x < 72) kvs[threadIdx.x] = kvb[(size_t)g * 72 + threadIdx.x];
    __syncthreads();

    const float* __restrict__ src = (g < 32) ? qkv : agg;
    const float* __restrict__ base = src + (size_t)(24 * (g & 31)) * NPIX;

    float q[8];
#pragma unroll
    for (int d = 0; d < 8; ++d) q[d] = fmaxf(0.0f, base[(size_t)d * NPIX + n]);

    float o[9] = {};
#pragma unroll
    for (int d = 0; d < 8; ++d) {
        float qd = q[d];
#pragma unroll
        for (int e = 0; e < 9; ++e) o[e] += qd * kvs[d * 9 + e];
    }
    float den = o[8] + 1e-15f;

    float* __restrict__ dst = att + (size_t)(g * 8) * NPIX + n;
#pragma unroll
    for (int e = 0; e < 8; ++e) dst[(size_t)e * NPIX] = o[e] / den;
}

// ---------------------------------------------------------------------------
extern "C" void kernel_launch(void* const* d_in, const int* in_sizes, int n_in,
                              void* d_out, int out_size, void* d_ws, size_t ws_size,
                              hipStream_t stream) {
    const float* x      = (const float*)d_in[0];
    const float* w_qkv  = (const float*)d_in[1];
    const float* w_dw   = (const float*)d_in[2];
    const float* w_pw   = (const float*)d_in[3];
    const float* w_proj = (const float*)d_in[4];
    const float* bn_g   = (const float*)d_in[5];
    const float* bn_b   = (const float*)d_in[6];
    const float* bn_m   = (const float*)d_in[7];
    const float* bn_v   = (const float*)d_in[8];
    float* out = (float*)d_out;

    // Batch-sequential fp32 intermediates (~32.2 MiB ws).
    char* ws = (char*)d_ws;
    float* qkv = (float*)ws;                        // 768*4096*4  = 12582912 B
    float* agg = (float*)(ws + 12582912ull);        // 12582912 B
    float* att = (float*)(ws + 25165824ull);        // 512*4096*4  = 8388608 B
    float* kvb = (float*)(ws + 33554432ull);        // 64*72*4     = 18432 B

    for (int b = 0; b < 8; ++b) {
        const float* xb   = x   + (size_t)b * 256 * NPIX;
        float*       outb = out + (size_t)b * 256 * NPIX;

        // 1) qkv = w_qkv (768x256) @ x_b  -- pure fp32 (branch-critical path)
        gemm_f32<<<dim3(64, 6), dim3(256), 0, stream>>>(w_qkv, xb, qkv);

        // 2) agg = grouped-pw( depthwise-5x5( qkv ) )  -- fp32 exact
        dwpw<<<dim3(4, 4, 96), dim3(256), 0, stream>>>(qkv, w_dw, w_pw, agg);

        // 3) kv reduction per group  -- fp32
        kv_reduce<<<dim3(64), dim3(256), 0, stream>>>(qkv, agg, kvb);

        // 4) apply attention, normalize  -- fp32
        attn_apply<<<dim3(16, 64), dim3(256), 0, stream>>>(qkv, agg, kvb, att);

        // 5) out_b = BN( w_proj (256x512) @ att )  -- split-bf16 MFMA (linear)
        gemm_bn<<<dim3(64, 4), dim3(256), 0, stream>>>(
            w_proj, att, outb, 256, 512, bn_g, bn_b, bn_m, bn_v);
    }
}

// Round 7
// 497.376 us; speedup vs baseline: 5.0877x; 5.0877x over previous
//
#include <hip/hip_runtime.h>

#define NPIX 4096   // 64*64

// ---------------------------------------------------------------------------
// fp32 SGEMM, LDS-tiled: C[b][m][n] = sum_k A[m][k]*B[b][k][n] (+ optional BN).
// Tile 128(m) x 128(n), TK=16. 256 threads (16x16); each thread 8m x (4+4)n.
// grid = (NPIX/128, M/128, batch)
// ---------------------------------------------------------------------------
__global__ __launch_bounds__(256) void sgemm(
    const float* __restrict__ A,   // [M][K]
    const float* __restrict__ Bm,  // [batch][K][NPIX]
    float* __restrict__ C,         // [batch][M][NPIX]
    int M, int K,
    const float* __restrict__ bn_g, const float* __restrict__ bn_b,
    const float* __restrict__ bn_m, const float* __restrict__ bn_v)
{
    __shared__ float As[16][128];   // [k][m]
    __shared__ float Bs[16][128];   // [k][n]

    const int tid = threadIdx.x;
    const int tx  = tid & 15;       // n-chunk
    const int ty  = tid >> 4;       // m-chunk
    const int n0  = blockIdx.x * 128;
    const int m0  = blockIdx.y * 128;
    const int bz  = blockIdx.z;

    const float* __restrict__ Bp = Bm + (size_t)bz * K * NPIX;

    // staging assignments
    const int ar = tid >> 1;          // A row 0..127
    const int ac = (tid & 1) * 8;     // A k-offset 0 or 8
    const int bk = tid >> 4;          // B k-row 0..15
    const int bn4 = (tid & 15) * 4;   // B n-offset

    float acc[8][8] = {};

    for (int k0 = 0; k0 < K; k0 += 16) {
        // global loads (issue early; latency overlaps other waves' compute)
        const float* ap = A + (size_t)(m0 + ar) * K + k0 + ac;
        float4 ga0 = *(const float4*)(ap);
        float4 ga1 = *(const float4*)(ap + 4);
        const float* bp = Bp + (size_t)(k0 + bk) * NPIX + n0 + bn4;
        float4 gb0 = *(const float4*)(bp);
        float4 gb1 = *(const float4*)(bp + 64);

        __syncthreads();   // previous tile fully consumed

        // A: transpose-on-write -> As[k][m]
        As[ac + 0][ar] = ga0.x;
        As[ac + 1][ar] = ga0.y;
        As[ac + 2][ar] = ga0.z;
        As[ac + 3][ar] = ga0.w;
        As[ac + 4][ar] = ga1.x;
        As[ac + 5][ar] = ga1.y;
        As[ac + 6][ar] = ga1.z;
        As[ac + 7][ar] = ga1.w;
        // B: direct
        *(float4*)&Bs[bk][bn4]      = gb0;
        *(float4*)&Bs[bk][bn4 + 64] = gb1;

        __syncthreads();

#pragma unroll
        for (int kk = 0; kk < 16; ++kk) {
            float av[8], bv[8];
            *(float4*)&av[0] = *(const float4*)&As[kk][ty * 8];
            *(float4*)&av[4] = *(const float4*)&As[kk][ty * 8 + 4];
            *(float4*)&bv[0] = *(const float4*)&Bs[kk][tx * 4];
            *(float4*)&bv[4] = *(const float4*)&Bs[kk][tx * 4 + 64];
#pragma unroll
            for (int i = 0; i < 8; ++i)
#pragma unroll
                for (int j = 0; j < 8; ++j)
                    acc[i][j] = fmaf(av[i], bv[j], acc[i][j]);
        }
    }

    float* __restrict__ Cp = C + (size_t)bz * M * NPIX;
#pragma unroll
    for (int i = 0; i < 8; ++i) {
        const int m = m0 + ty * 8 + i;
        float sc = 1.0f, off = 0.0f;
        if (bn_g) {
            sc  = (1.0f / sqrtf(bn_v[m] + 1e-5f)) * bn_g[m];
            off = bn_b[m] - bn_m[m] * sc;
        }
        float4 v0, v1;
        v0.x = acc[i][0] * sc + off;  v0.y = acc[i][1] * sc + off;
        v0.z = acc[i][2] * sc + off;  v0.w = acc[i][3] * sc + off;
        v1.x = acc[i][4] * sc + off;  v1.y = acc[i][5] * sc + off;
        v1.z = acc[i][6] * sc + off;  v1.w = acc[i][7] * sc + off;
        *(float4*)(Cp + (size_t)m * NPIX + n0 + tx * 4)      = v0;
        *(float4*)(Cp + (size_t)m * NPIX + n0 + 64 + tx * 4) = v1;
    }
}

// ---------------------------------------------------------------------------
// Fused depthwise 5x5 (pad 2) + grouped pointwise 8->8, fp32, batched.
// grid = (4, 4, batch*96); block = 256 (16x16 pixels)
// ---------------------------------------------------------------------------
__global__ __launch_bounds__(256) void dwpw(
    const float* __restrict__ qkv,   // [batch][768][NPIX]
    const float* __restrict__ w_dw,  // [768][25]
    const float* __restrict__ w_pw,  // [768][8]
    float* __restrict__ agg)         // [batch][768][NPIX]
{
    __shared__ float sm[8][20][20];
    __shared__ float wdw[8][25];
    __shared__ float wpw[8][8];

    const int tid = threadIdx.x;
    const int p   = blockIdx.z % 96;
    const int b   = blockIdx.z / 96;
    const int y0  = blockIdx.y * 16;
    const int x0  = blockIdx.x * 16;

    const float* __restrict__ src = qkv + ((size_t)b * 768 + 8 * p) * NPIX;

    for (int i = tid; i < 8 * 400; i += 256) {
        int c = i / 400, r = i % 400;
        int sy = r / 20, sx = r % 20;
        int gy = y0 + sy - 2, gx = x0 + sx - 2;
        float v = 0.0f;
        if ((unsigned)gy < 64u && (unsigned)gx < 64u)
            v = src[(size_t)c * NPIX + gy * 64 + gx];
        sm[c][sy][sx] = v;
    }
    if (tid < 200) {
        int c = tid / 25, t = tid % 25;
        wdw[c][t] = w_dw[(size_t)(8 * p + c) * 25 + t];
    }
    if (tid < 64) {
        int o = tid / 8, i = tid % 8;
        wpw[o][i] = w_pw[(size_t)(8 * p + o) * 8 + i];
    }
    __syncthreads();

    const int ty = tid >> 4, tx = tid & 15;

    float d[8];
#pragma unroll
    for (int c = 0; c < 8; ++c) {
        float s = 0.0f;
#pragma unroll
        for (int ky = 0; ky < 5; ++ky)
#pragma unroll
            for (int kx = 0; kx < 5; ++kx)
                s += wdw[c][ky * 5 + kx] * sm[c][ty + ky][tx + kx];
        d[c] = s;
    }

    float* __restrict__ dst = agg + ((size_t)b * 768 + 8 * p) * NPIX + (y0 + ty) * 64 + (x0 + tx);
#pragma unroll
    for (int o = 0; o < 8; ++o) {
        float s = 0.0f;
#pragma unroll
        for (int i = 0; i < 8; ++i) s += wpw[o][i] * d[i];
        dst[(size_t)o * NPIX] = s;
    }
}

// ---------------------------------------------------------------------------
// kv[b][g][d][e] = sum_n relu(k[n][d]) * v'[n][e]   (v'[:,8] = 1)
// grid = (64, batch); block = 256. One block per (g,b), no atomics.
// ---------------------------------------------------------------------------
__global__ __launch_bounds__(256) void kv_reduce(
    const float* __restrict__ qkv, const float* __restrict__ agg,
    float* __restrict__ kvb)      // [batch][64][72]
{
    const int g = blockIdx.x, b = blockIdx.y;
    const float* __restrict__ src = (g < 32) ? qkv : agg;
    const float* __restrict__ base = src + ((size_t)b * 768 + 24 * (g & 31)) * NPIX;

    float acc[72];
#pragma unroll
    for (int i = 0; i < 72; ++i) acc[i] = 0.0f;

    for (int n = threadIdx.x; n < NPIX; n += 256) {
        float kf[8], vf[8];
#pragma unroll
        for (int d = 0; d < 8; ++d) kf[d] = fmaxf(0.0f, base[(size_t)(8 + d) * NPIX + n]);
#pragma unroll
        for (int e = 0; e < 8; ++e) vf[e] = base[(size_t)(16 + e) * NPIX + n];
#pragma unroll
        for (int d = 0; d < 8; ++d) {
#pragma unroll
            for (int e = 0; e < 8; ++e) acc[d * 9 + e] += kf[d] * vf[e];
            acc[d * 9 + 8] += kf[d];
        }
    }

    const int lane = threadIdx.x & 63;
    const int wv   = threadIdx.x >> 6;
#pragma unroll
    for (int i = 0; i < 72; ++i) {
        float v = acc[i];
        v += __shfl_xor(v, 32, 64);
        v += __shfl_xor(v, 16, 64);
        v += __shfl_xor(v, 8, 64);
        v += __shfl_xor(v, 4, 64);
        v += __shfl_xor(v, 2, 64);
        v += __shfl_xor(v, 1, 64);
        acc[i] = v;
    }
    __shared__ float red[4][72];
    if (lane == 0) {
#pragma unroll
        for (int i = 0; i < 72; ++i) red[wv][i] = acc[i];
    }
    __syncthreads();
    if (threadIdx.x < 72)
        kvb[((size_t)b * 64 + g) * 72 + threadIdx.x] =
            red[0][threadIdx.x] + red[1][threadIdx.x] +
            red[2][threadIdx.x] + red[3][threadIdx.x];
}

// ---------------------------------------------------------------------------
// att[b][g*8+e][n] = (sum_d relu(q[n][d]) kv[d][e]) / (sum_d relu(q[n][d]) kv[d][8] + eps)
// grid = (16, 64, batch); block = 256
// ---------------------------------------------------------------------------
__global__ __launch_bounds__(256) void attn_apply(
    const float* __restrict__ qkv, const float* __restrict__ agg,
    const float* __restrict__ kvb,
    float* __restrict__ att)      // [batch][512][NPIX]
{
    const int g = blockIdx.y, b = blockIdx.z;
    const int n = blockIdx.x * 256 + threadIdx.x;

    __shared__ float kvs[72];
    if (threadIdx.x < 72) kvs[threadIdx.x] = kvb[((size_t)b * 64 + g) * 72 + threadIdx.x];
    __syncthreads();

    const float* __restrict__ src = (g < 32) ? qkv : agg;
    const float* __restrict__ base = src + ((size_t)b * 768 + 24 * (g & 31)) * NPIX;

    float q[8];
#pragma unroll
    for (int d = 0; d < 8; ++d) q[d] = fmaxf(0.0f, base[(size_t)d * NPIX + n]);

    float o[9] = {};
#pragma unroll
    for (int d = 0; d < 8; ++d) {
        float qd = q[d];
#pragma unroll
        for (int e = 0; e < 9; ++e) o[e] += qd * kvs[d * 9 + e];
    }
    float den = o[8] + 1e-15f;

    float* __restrict__ dst = att + ((size_t)b * 512 + g * 8) * NPIX + n;
#pragma unroll
    for (int e = 0; e < 8; ++e) dst[(size_t)e * NPIX] = o[e] / den;
}

// ---------------------------------------------------------------------------
extern "C" void kernel_launch(void* const* d_in, const int* in_sizes, int n_in,
                              void* d_out, int out_size, void* d_ws, size_t ws_size,
                              hipStream_t stream) {
    const float* x      = (const float*)d_in[0];
    const float* w_qkv  = (const float*)d_in[1];
    const float* w_dw   = (const float*)d_in[2];
    const float* w_pw   = (const float*)d_in[3];
    const float* w_proj = (const float*)d_in[4];
    const float* bn_g   = (const float*)d_in[5];
    const float* bn_b   = (const float*)d_in[6];
    const float* bn_m   = (const float*)d_in[7];
    const float* bn_v   = (const float*)d_in[8];
    float* out = (float*)d_out;

    // Full-batch fp32 intermediates: exactly 256 MiB (ws >= 256 MiB,
    // established rounds 4/5). kvb (147 KB) lives in d_out: written by
    // kv_reduce, read by attn_apply, then proj sgemm overwrites all of d_out.
    char* ws = (char*)d_ws;
    float* qkv = (float*)ws;                        // 8*768*4096*4 = 100663296 B
    float* agg = (float*)(ws + 100663296ull);       // 100663296 B
    float* att = (float*)(ws + 201326592ull);       // 8*512*4096*4 = 67108864 B
    float* kvb = (float*)d_out;                     // 8*64*72*4 = 147456 B

    // 1) qkv = w_qkv (768x256) @ x
    sgemm<<<dim3(32, 6, 8), dim3(256), 0, stream>>>(
        w_qkv, x, qkv, 768, 256, nullptr, nullptr, nullptr, nullptr);

    // 2) agg = grouped-pw( depthwise-5x5( qkv ) )
    dwpw<<<dim3(4, 4, 8 * 96), dim3(256), 0, stream>>>(qkv, w_dw, w_pw, agg);

    // 3) kv reduction per (g, b)
    kv_reduce<<<dim3(64, 8), dim3(256), 0, stream>>>(qkv, agg, kvb);

    // 4) apply attention, normalize
    attn_apply<<<dim3(16, 64, 8), dim3(256), 0, stream>>>(qkv, agg, kvb, att);

    // 5) out = BN( w_proj (256x512) @ att )   (overwrites all of d_out)
    sgemm<<<dim3(32, 2, 8), dim3(256), 0, stream>>>(
        w_proj, att, out, 256, 512, bn_g, bn_b, bn_m, bn_v);
}

// Round 8
// 488.050 us; speedup vs baseline: 5.1849x; 1.0191x over previous
//
#include <hip/hip_runtime.h>

typedef __bf16 bf16;
typedef __bf16 bf16x4 __attribute__((ext_vector_type(4)));
typedef __bf16 bf16x8 __attribute__((ext_vector_type(8)));
typedef float f32x4 __attribute__((ext_vector_type(4)));

#define NPIX 4096   // 64*64

// ---------------------------------------------------------------------------
// split_x: x[b][k][pix] fp32 -> 3 bf16 planes xT[b][pix][k] (h+m+l == x exact).
// Each lane owns one pixel row: coalesced k-strided reads, 64B-merged writes.
// grid = (16, 8, 8); block = 256
// ---------------------------------------------------------------------------
__global__ __launch_bounds__(256) void split_x(
    const float* __restrict__ x,   // [8][256][NPIX]
    bf16* __restrict__ xTh, bf16* __restrict__ xTm, bf16* __restrict__ xTl)
{
    const int pix = blockIdx.x * 256 + threadIdx.x;
    const int k0  = blockIdx.y * 32;
    const int b   = blockIdx.z;

    const float* __restrict__ src = x + ((size_t)b * 256 + k0) * NPIX + pix;
    float v[32];
#pragma unroll
    for (int kk = 0; kk < 32; ++kk) v[kk] = src[(size_t)kk * NPIX];

    const size_t drow = ((size_t)b * NPIX + pix) * 256 + k0;
#pragma unroll
    for (int c = 0; c < 4; ++c) {
        bf16x8 vh, vm, vl;
#pragma unroll
        for (int j = 0; j < 8; ++j) {
            float val = v[c * 8 + j];
            bf16 h = (bf16)val; float r  = val - (float)h;
            bf16 m = (bf16)r;   float r2 = r - (float)m;
            vh[j] = h; vm[j] = m; vl[j] = (bf16)r2;
        }
        *(bf16x8*)(xTh + drow + c * 8) = vh;
        *(bf16x8*)(xTm + drow + c * 8) = vm;
        *(bf16x8*)(xTl + drow + c * 8) = vl;
    }
}

// ---------------------------------------------------------------------------
// qkv GEMM via split-3 bf16 MFMA (6 products == fp32-accurate).
// C[b][m][n] = sum_k A[m][k] * x[b][k][n].  M=768, K=256.
// Block: 128m x 128n, 4 waves (2x2 of 64x64), BK=32.
// A: fp32 global -> split in-reg -> LDS 3 planes. B: direct-global bf16x8
// fragments from pre-split transposed planes.
// grid = (32, 6, 8); block = 256
// ---------------------------------------------------------------------------
__global__ __launch_bounds__(256, 2) void qkv_mfma(
    const float* __restrict__ A,     // [768][256]
    const bf16* __restrict__ xTh,    // [8][NPIX][256]
    const bf16* __restrict__ xTm,
    const bf16* __restrict__ xTl,
    float* __restrict__ C)           // [8][768][NPIX]
{
    __shared__ bf16 As[3][128][40];  // padded rows (80 B) break bank alignment

    const int tid  = threadIdx.x;
    const int lane = tid & 63;
    const int wv   = tid >> 6;
    const int col  = lane & 15;
    const int quad = lane >> 4;
    const int wm   = (wv >> 1) * 64;
    const int wn   = (wv & 1) * 64;
    const int n0   = blockIdx.x * 128;
    const int m0   = blockIdx.y * 128;
    const int b    = blockIdx.z;

    const int arow = tid >> 1;          // 0..127
    const int akc  = (tid & 1) * 16;    // 0 or 16

    const size_t xoff = ((size_t)b * NPIX + n0 + wn) * 256;

    f32x4 acc[4][4] = {};

    // prologue: A-tile k0=0 into regs
    float av[16];
    {
        const float* ap = A + (size_t)(m0 + arow) * 256 + akc;
        *(float4*)&av[0]  = *(const float4*)(ap);
        *(float4*)&av[4]  = *(const float4*)(ap + 4);
        *(float4*)&av[8]  = *(const float4*)(ap + 8);
        *(float4*)&av[12] = *(const float4*)(ap + 12);
    }

    for (int k0 = 0; k0 < 256; k0 += 32) {
        __syncthreads();   // previous tile's fragments consumed

        // split A regs -> LDS (3 planes, packed b64 writes)
#pragma unroll
        for (int c = 0; c < 4; ++c) {
            bf16x4 vh, vm, vl;
#pragma unroll
            for (int j = 0; j < 4; ++j) {
                float val = av[c * 4 + j];
                bf16 h = (bf16)val; float r  = val - (float)h;
                bf16 m = (bf16)r;   float r2 = r - (float)m;
                vh[j] = h; vm[j] = m; vl[j] = (bf16)r2;
            }
            *(bf16x4*)&As[0][arow][akc + c * 4] = vh;
            *(bf16x4*)&As[1][arow][akc + c * 4] = vm;
            *(bf16x4*)&As[2][arow][akc + c * 4] = vl;
        }

        // prefetch next A-tile
        if (k0 + 32 < 256) {
            const float* ap = A + (size_t)(m0 + arow) * 256 + k0 + 32 + akc;
            *(float4*)&av[0]  = *(const float4*)(ap);
            *(float4*)&av[4]  = *(const float4*)(ap + 4);
            *(float4*)&av[8]  = *(const float4*)(ap + 8);
            *(float4*)&av[12] = *(const float4*)(ap + 12);
        }

        __syncthreads();   // As ready

        // B fragments: direct from global (16 B contiguous per lane)
        bf16x8 bh[4], bm[4], bl[4];
#pragma unroll
        for (int t = 0; t < 4; ++t) {
            const size_t brow = xoff + (size_t)(t * 16 + col) * 256 + k0 + quad * 8;
            bh[t] = *(const bf16x8*)(xTh + brow);
            bm[t] = *(const bf16x8*)(xTm + brow);
            bl[t] = *(const bf16x8*)(xTl + brow);
        }
        // A fragments from LDS
        bf16x8 af[4][3];
#pragma unroll
        for (int s = 0; s < 4; ++s)
#pragma unroll
            for (int p = 0; p < 3; ++p)
                af[s][p] = *(const bf16x8*)&As[p][wm + s * 16 + col][quad * 8];

        // 6 products, small-magnitude first; product-major for MFMA pipelining
#pragma unroll
        for (int t = 0; t < 4; ++t)
#pragma unroll
            for (int s = 0; s < 4; ++s)
                acc[s][t] = __builtin_amdgcn_mfma_f32_16x16x32_bf16(af[s][2], bh[t], acc[s][t], 0, 0, 0);
#pragma unroll
        for (int t = 0; t < 4; ++t)
#pragma unroll
            for (int s = 0; s < 4; ++s)
                acc[s][t] = __builtin_amdgcn_mfma_f32_16x16x32_bf16(af[s][0], bl[t], acc[s][t], 0, 0, 0);
#pragma unroll
        for (int t = 0; t < 4; ++t)
#pragma unroll
            for (int s = 0; s < 4; ++s)
                acc[s][t] = __builtin_amdgcn_mfma_f32_16x16x32_bf16(af[s][1], bm[t], acc[s][t], 0, 0, 0);
#pragma unroll
        for (int t = 0; t < 4; ++t)
#pragma unroll
            for (int s = 0; s < 4; ++s)
                acc[s][t] = __builtin_amdgcn_mfma_f32_16x16x32_bf16(af[s][1], bh[t], acc[s][t], 0, 0, 0);
#pragma unroll
        for (int t = 0; t < 4; ++t)
#pragma unroll
            for (int s = 0; s < 4; ++s)
                acc[s][t] = __builtin_amdgcn_mfma_f32_16x16x32_bf16(af[s][0], bm[t], acc[s][t], 0, 0, 0);
#pragma unroll
        for (int t = 0; t < 4; ++t)
#pragma unroll
            for (int s = 0; s < 4; ++s)
                acc[s][t] = __builtin_amdgcn_mfma_f32_16x16x32_bf16(af[s][0], bh[t], acc[s][t], 0, 0, 0);
    }

    float* __restrict__ Cp = C + (size_t)b * 768 * NPIX;
#pragma unroll
    for (int s = 0; s < 4; ++s)
#pragma unroll
        for (int t = 0; t < 4; ++t)
#pragma unroll
            for (int r = 0; r < 4; ++r) {
                const int m = m0 + wm + s * 16 + quad * 4 + r;
                const int n = n0 + wn + t * 16 + col;
                Cp[(size_t)m * NPIX + n] = acc[s][t][r];
            }
}

// ---------------------------------------------------------------------------
// fp32 SGEMM (proj), LDS-tiled, BN epilogue — unchanged from round 7.
// grid = (32, 2, 8); block = 256
// ---------------------------------------------------------------------------
__global__ __launch_bounds__(256) void sgemm(
    const float* __restrict__ A,   // [M][K]
    const float* __restrict__ Bm,  // [batch][K][NPIX]
    float* __restrict__ C,         // [batch][M][NPIX]
    int M, int K,
    const float* __restrict__ bn_g, const float* __restrict__ bn_b,
    const float* __restrict__ bn_m, const float* __restrict__ bn_v)
{
    __shared__ float As[16][128];   // [k][m]
    __shared__ float Bs[16][128];   // [k][n]

    const int tid = threadIdx.x;
    const int tx  = tid & 15;
    const int ty  = tid >> 4;
    const int n0  = blockIdx.x * 128;
    const int m0  = blockIdx.y * 128;
    const int bz  = blockIdx.z;

    const float* __restrict__ Bp = Bm + (size_t)bz * K * NPIX;

    const int ar = tid >> 1;
    const int ac = (tid & 1) * 8;
    const int bk = tid >> 4;
    const int bn4 = (tid & 15) * 4;

    float acc[8][8] = {};

    for (int k0 = 0; k0 < K; k0 += 16) {
        const float* ap = A + (size_t)(m0 + ar) * K + k0 + ac;
        float4 ga0 = *(const float4*)(ap);
        float4 ga1 = *(const float4*)(ap + 4);
        const float* bp = Bp + (size_t)(k0 + bk) * NPIX + n0 + bn4;
        float4 gb0 = *(const float4*)(bp);
        float4 gb1 = *(const float4*)(bp + 64);

        __syncthreads();

        As[ac + 0][ar] = ga0.x;  As[ac + 1][ar] = ga0.y;
        As[ac + 2][ar] = ga0.z;  As[ac + 3][ar] = ga0.w;
        As[ac + 4][ar] = ga1.x;  As[ac + 5][ar] = ga1.y;
        As[ac + 6][ar] = ga1.z;  As[ac + 7][ar] = ga1.w;
        *(float4*)&Bs[bk][bn4]      = gb0;
        *(float4*)&Bs[bk][bn4 + 64] = gb1;

        __syncthreads();

#pragma unroll
        for (int kk = 0; kk < 16; ++kk) {
            float avv[8], bvv[8];
            *(float4*)&avv[0] = *(const float4*)&As[kk][ty * 8];
            *(float4*)&avv[4] = *(const float4*)&As[kk][ty * 8 + 4];
            *(float4*)&bvv[0] = *(const float4*)&Bs[kk][tx * 4];
            *(float4*)&bvv[4] = *(const float4*)&Bs[kk][tx * 4 + 64];
#pragma unroll
            for (int i = 0; i < 8; ++i)
#pragma unroll
                for (int j = 0; j < 8; ++j)
                    acc[i][j] = fmaf(avv[i], bvv[j], acc[i][j]);
        }
    }

    float* __restrict__ Cp = C + (size_t)bz * M * NPIX;
#pragma unroll
    for (int i = 0; i < 8; ++i) {
        const int m = m0 + ty * 8 + i;
        float sc = 1.0f, off = 0.0f;
        if (bn_g) {
            sc  = (1.0f / sqrtf(bn_v[m] + 1e-5f)) * bn_g[m];
            off = bn_b[m] - bn_m[m] * sc;
        }
        float4 v0, v1;
        v0.x = acc[i][0] * sc + off;  v0.y = acc[i][1] * sc + off;
        v0.z = acc[i][2] * sc + off;  v0.w = acc[i][3] * sc + off;
        v1.x = acc[i][4] * sc + off;  v1.y = acc[i][5] * sc + off;
        v1.z = acc[i][6] * sc + off;  v1.w = acc[i][7] * sc + off;
        *(float4*)(Cp + (size_t)m * NPIX + n0 + tx * 4)      = v0;
        *(float4*)(Cp + (size_t)m * NPIX + n0 + 64 + tx * 4) = v1;
    }
}

// ---------------------------------------------------------------------------
// Fused depthwise 5x5 (pad 2) + grouped pointwise 8->8, fp32, batched.
// grid = (4, 4, batch*96); block = 256
// ---------------------------------------------------------------------------
__global__ __launch_bounds__(256) void dwpw(
    const float* __restrict__ qkv,   // [batch][768][NPIX]
    const float* __restrict__ w_dw,  // [768][25]
    const float* __restrict__ w_pw,  // [768][8]
    float* __restrict__ agg)         // [batch][768][NPIX]
{
    __shared__ float sm[8][20][20];
    __shared__ float wdw[8][25];
    __shared__ float wpw[8][8];

    const int tid = threadIdx.x;
    const int p   = blockIdx.z % 96;
    const int b   = blockIdx.z / 96;
    const int y0  = blockIdx.y * 16;
    const int x0  = blockIdx.x * 16;

    const float* __restrict__ src = qkv + ((size_t)b * 768 + 8 * p) * NPIX;

    for (int i = tid; i < 8 * 400; i += 256) {
        int c = i / 400, r = i % 400;
        int sy = r / 20, sx = r % 20;
        int gy = y0 + sy - 2, gx = x0 + sx - 2;
        float v = 0.0f;
        if ((unsigned)gy < 64u && (unsigned)gx < 64u)
            v = src[(size_t)c * NPIX + gy * 64 + gx];
        sm[c][sy][sx] = v;
    }
    if (tid < 200) {
        int c = tid / 25, t = tid % 25;
        wdw[c][t] = w_dw[(size_t)(8 * p + c) * 25 + t];
    }
    if (tid < 64) {
        int o = tid / 8, i = tid % 8;
        wpw[o][i] = w_pw[(size_t)(8 * p + o) * 8 + i];
    }
    __syncthreads();

    const int ty = tid >> 4, tx = tid & 15;

    float d[8];
#pragma unroll
    for (int c = 0; c < 8; ++c) {
        float s = 0.0f;
#pragma unroll
        for (int ky = 0; ky < 5; ++ky)
#pragma unroll
            for (int kx = 0; kx < 5; ++kx)
                s += wdw[c][ky * 5 + kx] * sm[c][ty + ky][tx + kx];
        d[c] = s;
    }

    float* __restrict__ dst = agg + ((size_t)b * 768 + 8 * p) * NPIX + (y0 + ty) * 64 + (x0 + tx);
#pragma unroll
    for (int o = 0; o < 8; ++o) {
        float s = 0.0f;
#pragma unroll
        for (int i = 0; i < 8; ++i) s += wpw[o][i] * d[i];
        dst[(size_t)o * NPIX] = s;
    }
}

// ---------------------------------------------------------------------------
// kv[b][g][d][e] = sum_n relu(k[n][d]) * v'[n][e]   (v'[:,8] = 1), float4.
// grid = (64, batch); block = 256
// ---------------------------------------------------------------------------
__global__ __launch_bounds__(256) void kv_reduce(
    const float* __restrict__ qkv, const float* __restrict__ agg,
    float* __restrict__ kvb)      // [batch][64][72]
{
    const int g = blockIdx.x, b = blockIdx.y;
    const float* __restrict__ src = (g < 32) ? qkv : agg;
    const float* __restrict__ base = src + ((size_t)b * 768 + 24 * (g & 31)) * NPIX;

    float acc[72];
#pragma unroll
    for (int i = 0; i < 72; ++i) acc[i] = 0.0f;

    for (int i4 = threadIdx.x; i4 < NPIX / 4; i4 += 256) {
        float4 kf[8], vf[8];
#pragma unroll
        for (int d = 0; d < 8; ++d) {
            float4 t = ((const float4*)(base + (size_t)(8 + d) * NPIX))[i4];
            kf[d].x = fmaxf(0.0f, t.x); kf[d].y = fmaxf(0.0f, t.y);
            kf[d].z = fmaxf(0.0f, t.z); kf[d].w = fmaxf(0.0f, t.w);
        }
#pragma unroll
        for (int e = 0; e < 8; ++e)
            vf[e] = ((const float4*)(base + (size_t)(16 + e) * NPIX))[i4];
#pragma unroll
        for (int d = 0; d < 8; ++d) {
#pragma unroll
            for (int e = 0; e < 8; ++e)
                acc[d * 9 + e] += kf[d].x * vf[e].x + kf[d].y * vf[e].y +
                                  kf[d].z * vf[e].z + kf[d].w * vf[e].w;
            acc[d * 9 + 8] += kf[d].x + kf[d].y + kf[d].z + kf[d].w;
        }
    }

    const int lane = threadIdx.x & 63;
    const int wv   = threadIdx.x >> 6;
#pragma unroll
    for (int i = 0; i < 72; ++i) {
        float v = acc[i];
        v += __shfl_xor(v, 32, 64);
        v += __shfl_xor(v, 16, 64);
        v += __shfl_xor(v, 8, 64);
        v += __shfl_xor(v, 4, 64);
        v += __shfl_xor(v, 2, 64);
        v += __shfl_xor(v, 1, 64);
        acc[i] = v;
    }
    __shared__ float red[4][72];
    if (lane == 0) {
#pragma unroll
        for (int i = 0; i < 72; ++i) red[wv][i] = acc[i];
    }
    __syncthreads();
    if (threadIdx.x < 72)
        kvb[((size_t)b * 64 + g) * 72 + threadIdx.x] =
            red[0][threadIdx.x] + red[1][threadIdx.x] +
            red[2][threadIdx.x] + red[3][threadIdx.x];
}

// ---------------------------------------------------------------------------
// att[b][g*8+e][n] = (sum_d relu(q) kv[d][e]) / (sum_d relu(q) kv[d][8] + eps)
// float4 over pixels. grid = (4, 64, batch); block = 256
// ---------------------------------------------------------------------------
__global__ __launch_bounds__(256) void attn_apply(
    const float* __restrict__ qkv, const float* __restrict__ agg,
    const float* __restrict__ kvb,
    float* __restrict__ att)      // [batch][512][NPIX]
{
    const int g = blockIdx.y, b = blockIdx.z;
    const int n4 = blockIdx.x * 256 + threadIdx.x;   // float4 index

    __shared__ float kvs[72];
    if (threadIdx.x < 72) kvs[threadIdx.x] = kvb[((size_t)b * 64 + g) * 72 + threadIdx.x];
    __syncthreads();

    const float* __restrict__ src = (g < 32) ? qkv : agg;
    const float* __restrict__ base = src + ((size_t)b * 768 + 24 * (g & 31)) * NPIX;

    float4 q[8];
#pragma unroll
    for (int d = 0; d < 8; ++d) {
        float4 t = ((const float4*)(base + (size_t)d * NPIX))[n4];
        q[d].x = fmaxf(0.0f, t.x); q[d].y = fmaxf(0.0f, t.y);
        q[d].z = fmaxf(0.0f, t.z); q[d].w = fmaxf(0.0f, t.w);
    }

    float4 o[9];
#pragma unroll
    for (int e = 0; e < 9; ++e) { o[e].x = 0; o[e].y = 0; o[e].z = 0; o[e].w = 0; }
#pragma unroll
    for (int d = 0; d < 8; ++d)
#pragma unroll
        for (int e = 0; e < 9; ++e) {
            float w = kvs[d * 9 + e];
            o[e].x += q[d].x * w; o[e].y += q[d].y * w;
            o[e].z += q[d].z * w; o[e].w += q[d].w * w;
        }
    float dx = o[8].x + 1e-15f, dy = o[8].y + 1e-15f;
    float dz = o[8].z + 1e-15f, dw = o[8].w + 1e-15f;

    float* __restrict__ dst = att + ((size_t)b * 512 + g * 8) * NPIX;
#pragma unroll
    for (int e = 0; e < 8; ++e) {
        float4 r;
        r.x = o[e].x / dx; r.y = o[e].y / dy;
        r.z = o[e].z / dz; r.w = o[e].w / dw;
        ((float4*)(dst + (size_t)e * NPIX))[n4] = r;
    }
}

// ---------------------------------------------------------------------------
extern "C" void kernel_launch(void* const* d_in, const int* in_sizes, int n_in,
                              void* d_out, int out_size, void* d_ws, size_t ws_size,
                              hipStream_t stream) {
    const float* x      = (const float*)d_in[0];
    const float* w_qkv  = (const float*)d_in[1];
    const float* w_dw   = (const float*)d_in[2];
    const float* w_pw   = (const float*)d_in[3];
    const float* w_proj = (const float*)d_in[4];
    const float* bn_g   = (const float*)d_in[5];
    const float* bn_b   = (const float*)d_in[6];
    const float* bn_m   = (const float*)d_in[7];
    const float* bn_v   = (const float*)d_in[8];
    float* out = (float*)d_out;

    // ws: qkv 96 MiB + agg 96 MiB + att 64 MiB = 256 MiB (known to fit).
    // xT split planes (3 x 16 MiB) live in the att region until attn_apply.
    // kvb (147 KB) lives in d_out (kv_reduce -> attn_apply -> proj overwrites).
    char* ws = (char*)d_ws;
    float* qkv = (float*)ws;                        // 100663296 B
    float* agg = (float*)(ws + 100663296ull);       // 100663296 B
    char*  attc = ws + 201326592ull;                // 67108864 B
    float* att = (float*)attc;
    bf16*  xTh = (bf16*)attc;                       // 16777216 B
    bf16*  xTm = (bf16*)(attc + 16777216ull);       // 16777216 B
    bf16*  xTl = (bf16*)(attc + 33554432ull);       // 16777216 B
    float* kvb = (float*)d_out;

    // 0) split + transpose x into 3 bf16 planes (h+m+l == x exactly)
    split_x<<<dim3(16, 8, 8), dim3(256), 0, stream>>>(x, xTh, xTm, xTl);

    // 1) qkv = w_qkv @ x  (split-3 MFMA, fp32-accurate)
    qkv_mfma<<<dim3(32, 6, 8), dim3(256), 0, stream>>>(w_qkv, xTh, xTm, xTl, qkv);

    // 2) agg = grouped-pw( depthwise-5x5( qkv ) )
    dwpw<<<dim3(4, 4, 8 * 96), dim3(256), 0, stream>>>(qkv, w_dw, w_pw, agg);

    // 3) kv reduction per (g, b)
    kv_reduce<<<dim3(64, 8), dim3(256), 0, stream>>>(qkv, agg, kvb);

    // 4) apply attention, normalize (overwrites xT region — xT dead by now)
    attn_apply<<<dim3(4, 64, 8), dim3(256), 0, stream>>>(qkv, agg, kvb, att);

    // 5) out = BN( w_proj @ att )  (overwrites all of d_out)
    sgemm<<<dim3(32, 2, 8), dim3(256), 0, stream>>>(
        w_proj, att, out, 256, 512, bn_g, bn_b, bn_m, bn_v);
}

// Round 9
// 472.220 us; speedup vs baseline: 5.3587x; 1.0335x over previous
//
#include <hip/hip_runtime.h>

typedef __bf16 bf16;
typedef __bf16 bf16x4 __attribute__((ext_vector_type(4)));
typedef __bf16 bf16x8 __attribute__((ext_vector_type(8)));
typedef float f32x4 __attribute__((ext_vector_type(4)));

#define NPIX 4096   // 64*64

// ---------------------------------------------------------------------------
// split_x: x[b][k][pix] fp32 -> 3 bf16 planes xT[b][pix][k] (h+m+l == x exact).
// grid = (16, 8, 8); block = 256
// ---------------------------------------------------------------------------
__global__ __launch_bounds__(256) void split_x(
    const float* __restrict__ x,   // [8][256][NPIX]
    bf16* __restrict__ xTh, bf16* __restrict__ xTm, bf16* __restrict__ xTl)
{
    const int pix = blockIdx.x * 256 + threadIdx.x;
    const int k0  = blockIdx.y * 32;
    const int b   = blockIdx.z;

    const float* __restrict__ src = x + ((size_t)b * 256 + k0) * NPIX + pix;
    float v[32];
#pragma unroll
    for (int kk = 0; kk < 32; ++kk) v[kk] = src[(size_t)kk * NPIX];

    const size_t drow = ((size_t)b * NPIX + pix) * 256 + k0;
#pragma unroll
    for (int c = 0; c < 4; ++c) {
        bf16x8 vh, vm, vl;
#pragma unroll
        for (int j = 0; j < 8; ++j) {
            float val = v[c * 8 + j];
            bf16 h = (bf16)val; float r  = val - (float)h;
            bf16 m = (bf16)r;   float r2 = r - (float)m;
            vh[j] = h; vm[j] = m; vl[j] = (bf16)r2;
        }
        *(bf16x8*)(xTh + drow + c * 8) = vh;
        *(bf16x8*)(xTm + drow + c * 8) = vm;
        *(bf16x8*)(xTl + drow + c * 8) = vl;
    }
}

// ---------------------------------------------------------------------------
// qkv GEMM via split-3 bf16 MFMA (6 products == fp32-accurate). Unchanged.
// grid = (32, 6, 8); block = 256
// ---------------------------------------------------------------------------
__global__ __launch_bounds__(256, 2) void qkv_mfma(
    const float* __restrict__ A,     // [768][256]
    const bf16* __restrict__ xTh,    // [8][NPIX][256]
    const bf16* __restrict__ xTm,
    const bf16* __restrict__ xTl,
    float* __restrict__ C)           // [8][768][NPIX]
{
    __shared__ bf16 As[3][128][40];

    const int tid  = threadIdx.x;
    const int lane = tid & 63;
    const int wv   = tid >> 6;
    const int col  = lane & 15;
    const int quad = lane >> 4;
    const int wm   = (wv >> 1) * 64;
    const int wn   = (wv & 1) * 64;
    const int n0   = blockIdx.x * 128;
    const int m0   = blockIdx.y * 128;
    const int b    = blockIdx.z;

    const int arow = tid >> 1;
    const int akc  = (tid & 1) * 16;

    const size_t xoff = ((size_t)b * NPIX + n0 + wn) * 256;

    f32x4 acc[4][4] = {};

    float av[16];
    {
        const float* ap = A + (size_t)(m0 + arow) * 256 + akc;
        *(float4*)&av[0]  = *(const float4*)(ap);
        *(float4*)&av[4]  = *(const float4*)(ap + 4);
        *(float4*)&av[8]  = *(const float4*)(ap + 8);
        *(float4*)&av[12] = *(const float4*)(ap + 12);
    }

    for (int k0 = 0; k0 < 256; k0 += 32) {
        __syncthreads();

#pragma unroll
        for (int c = 0; c < 4; ++c) {
            bf16x4 vh, vm, vl;
#pragma unroll
            for (int j = 0; j < 4; ++j) {
                float val = av[c * 4 + j];
                bf16 h = (bf16)val; float r  = val - (float)h;
                bf16 m = (bf16)r;   float r2 = r - (float)m;
                vh[j] = h; vm[j] = m; vl[j] = (bf16)r2;
            }
            *(bf16x4*)&As[0][arow][akc + c * 4] = vh;
            *(bf16x4*)&As[1][arow][akc + c * 4] = vm;
            *(bf16x4*)&As[2][arow][akc + c * 4] = vl;
        }

        if (k0 + 32 < 256) {
            const float* ap = A + (size_t)(m0 + arow) * 256 + k0 + 32 + akc;
            *(float4*)&av[0]  = *(const float4*)(ap);
            *(float4*)&av[4]  = *(const float4*)(ap + 4);
            *(float4*)&av[8]  = *(const float4*)(ap + 8);
            *(float4*)&av[12] = *(const float4*)(ap + 12);
        }

        __syncthreads();

        bf16x8 bh[4], bm[4], bl[4];
#pragma unroll
        for (int t = 0; t < 4; ++t) {
            const size_t brow = xoff + (size_t)(t * 16 + col) * 256 + k0 + quad * 8;
            bh[t] = *(const bf16x8*)(xTh + brow);
            bm[t] = *(const bf16x8*)(xTm + brow);
            bl[t] = *(const bf16x8*)(xTl + brow);
        }
        bf16x8 af[4][3];
#pragma unroll
        for (int s = 0; s < 4; ++s)
#pragma unroll
            for (int p = 0; p < 3; ++p)
                af[s][p] = *(const bf16x8*)&As[p][wm + s * 16 + col][quad * 8];

#pragma unroll
        for (int t = 0; t < 4; ++t)
#pragma unroll
            for (int s = 0; s < 4; ++s)
                acc[s][t] = __builtin_amdgcn_mfma_f32_16x16x32_bf16(af[s][2], bh[t], acc[s][t], 0, 0, 0);
#pragma unroll
        for (int t = 0; t < 4; ++t)
#pragma unroll
            for (int s = 0; s < 4; ++s)
                acc[s][t] = __builtin_amdgcn_mfma_f32_16x16x32_bf16(af[s][0], bl[t], acc[s][t], 0, 0, 0);
#pragma unroll
        for (int t = 0; t < 4; ++t)
#pragma unroll
            for (int s = 0; s < 4; ++s)
                acc[s][t] = __builtin_amdgcn_mfma_f32_16x16x32_bf16(af[s][1], bm[t], acc[s][t], 0, 0, 0);
#pragma unroll
        for (int t = 0; t < 4; ++t)
#pragma unroll
            for (int s = 0; s < 4; ++s)
                acc[s][t] = __builtin_amdgcn_mfma_f32_16x16x32_bf16(af[s][1], bh[t], acc[s][t], 0, 0, 0);
#pragma unroll
        for (int t = 0; t < 4; ++t)
#pragma unroll
            for (int s = 0; s < 4; ++s)
                acc[s][t] = __builtin_amdgcn_mfma_f32_16x16x32_bf16(af[s][0], bm[t], acc[s][t], 0, 0, 0);
#pragma unroll
        for (int t = 0; t < 4; ++t)
#pragma unroll
            for (int s = 0; s < 4; ++s)
                acc[s][t] = __builtin_amdgcn_mfma_f32_16x16x32_bf16(af[s][0], bh[t], acc[s][t], 0, 0, 0);
    }

    float* __restrict__ Cp = C + (size_t)b * 768 * NPIX;
#pragma unroll
    for (int s = 0; s < 4; ++s)
#pragma unroll
        for (int t = 0; t < 4; ++t)
#pragma unroll
            for (int r = 0; r < 4; ++r) {
                const int m = m0 + wm + s * 16 + quad * 4 + r;
                const int n = n0 + wn + t * 16 + col;
                Cp[(size_t)m * NPIX + n] = acc[s][t][r];
            }
}

// ---------------------------------------------------------------------------
// Fused depthwise 5x5 (pad 2) + grouped pointwise 8->8, fp32. Unchanged.
// grid = (4, 4, batch*96); block = 256
// ---------------------------------------------------------------------------
__global__ __launch_bounds__(256) void dwpw(
    const float* __restrict__ qkv,   // [batch][768][NPIX]
    const float* __restrict__ w_dw,  // [768][25]
    const float* __restrict__ w_pw,  // [768][8]
    float* __restrict__ agg)         // [batch][768][NPIX]
{
    __shared__ float sm[8][20][20];
    __shared__ float wdw[8][25];
    __shared__ float wpw[8][8];

    const int tid = threadIdx.x;
    const int p   = blockIdx.z % 96;
    const int b   = blockIdx.z / 96;
    const int y0  = blockIdx.y * 16;
    const int x0  = blockIdx.x * 16;

    const float* __restrict__ src = qkv + ((size_t)b * 768 + 8 * p) * NPIX;

    for (int i = tid; i < 8 * 400; i += 256) {
        int c = i / 400, r = i % 400;
        int sy = r / 20, sx = r % 20;
        int gy = y0 + sy - 2, gx = x0 + sx - 2;
        float v = 0.0f;
        if ((unsigned)gy < 64u && (unsigned)gx < 64u)
            v = src[(size_t)c * NPIX + gy * 64 + gx];
        sm[c][sy][sx] = v;
    }
    if (tid < 200) {
        int c = tid / 25, t = tid % 25;
        wdw[c][t] = w_dw[(size_t)(8 * p + c) * 25 + t];
    }
    if (tid < 64) {
        int o = tid / 8, i = tid % 8;
        wpw[o][i] = w_pw[(size_t)(8 * p + o) * 8 + i];
    }
    __syncthreads();

    const int ty = tid >> 4, tx = tid & 15;

    float d[8];
#pragma unroll
    for (int c = 0; c < 8; ++c) {
        float s = 0.0f;
#pragma unroll
        for (int ky = 0; ky < 5; ++ky)
#pragma unroll
            for (int kx = 0; kx < 5; ++kx)
                s += wdw[c][ky * 5 + kx] * sm[c][ty + ky][tx + kx];
        d[c] = s;
    }

    float* __restrict__ dst = agg + ((size_t)b * 768 + 8 * p) * NPIX + (y0 + ty) * 64 + (x0 + tx);
#pragma unroll
    for (int o = 0; o < 8; ++o) {
        float s = 0.0f;
#pragma unroll
        for (int i = 0; i < 8; ++i) s += wpw[o][i] * d[i];
        dst[(size_t)o * NPIX] = s;
    }
}

// ---------------------------------------------------------------------------
// kv[b][g][d][e] = sum_n relu(k[n][d]) * v'[n][e]   (v'[:,8] = 1). Unchanged.
// grid = (64, batch); block = 256
// ---------------------------------------------------------------------------
__global__ __launch_bounds__(256) void kv_reduce(
    const float* __restrict__ qkv, const float* __restrict__ agg,
    float* __restrict__ kvb)      // [batch][64][72]
{
    const int g = blockIdx.x, b = blockIdx.y;
    const float* __restrict__ src = (g < 32) ? qkv : agg;
    const float* __restrict__ base = src + ((size_t)b * 768 + 24 * (g & 31)) * NPIX;

    float acc[72];
#pragma unroll
    for (int i = 0; i < 72; ++i) acc[i] = 0.0f;

    for (int i4 = threadIdx.x; i4 < NPIX / 4; i4 += 256) {
        float4 kf[8], vf[8];
#pragma unroll
        for (int d = 0; d < 8; ++d) {
            float4 t = ((const float4*)(base + (size_t)(8 + d) * NPIX))[i4];
            kf[d].x = fmaxf(0.0f, t.x); kf[d].y = fmaxf(0.0f, t.y);
            kf[d].z = fmaxf(0.0f, t.z); kf[d].w = fmaxf(0.0f, t.w);
        }
#pragma unroll
        for (int e = 0; e < 8; ++e)
            vf[e] = ((const float4*)(base + (size_t)(16 + e) * NPIX))[i4];
#pragma unroll
        for (int d = 0; d < 8; ++d) {
#pragma unroll
            for (int e = 0; e < 8; ++e)
                acc[d * 9 + e] += kf[d].x * vf[e].x + kf[d].y * vf[e].y +
                                  kf[d].z * vf[e].z + kf[d].w * vf[e].w;
            acc[d * 9 + 8] += kf[d].x + kf[d].y + kf[d].z + kf[d].w;
        }
    }

    const int lane = threadIdx.x & 63;
    const int wv   = threadIdx.x >> 6;
#pragma unroll
    for (int i = 0; i < 72; ++i) {
        float v = acc[i];
        v += __shfl_xor(v, 32, 64);
        v += __shfl_xor(v, 16, 64);
        v += __shfl_xor(v, 8, 64);
        v += __shfl_xor(v, 4, 64);
        v += __shfl_xor(v, 2, 64);
        v += __shfl_xor(v, 1, 64);
        acc[i] = v;
    }
    __shared__ float red[4][72];
    if (lane == 0) {
#pragma unroll
        for (int i = 0; i < 72; ++i) red[wv][i] = acc[i];
    }
    __syncthreads();
    if (threadIdx.x < 72)
        kvb[((size_t)b * 64 + g) * 72 + threadIdx.x] =
            red[0][threadIdx.x] + red[1][threadIdx.x] +
            red[2][threadIdx.x] + red[3][threadIdx.x];
}

// ---------------------------------------------------------------------------
// attn_fused: compute normalized attention output and write it TRANSPOSED as
// split-2 bf16 planes attT[b][pix][512] (h+m), ready as proj MFMA B-operand.
// out[k=g*8+e][n] = sum_d (relu(q[n][d])/den) * kv[d][e],
//   den = sum_d relu(q[n][d]) * kv[d][8] + 1e-15.
// Thread: pixel p = tid&31 (32-pixel tile), group-octet c = tid>>5.
// Per-thread writes are 128 B contiguous per plane -> full L2 lines.
// grid = (NPIX/32 = 128, batch); block = 256
// ---------------------------------------------------------------------------
__global__ __launch_bounds__(256) void attn_fused(
    const float* __restrict__ qkv, const float* __restrict__ agg,
    const float* __restrict__ kvb,   // [batch][64][72]
    bf16* __restrict__ attTh, bf16* __restrict__ attTm)  // [8][NPIX][512]
{
    const int b   = blockIdx.y;
    const int n0  = blockIdx.x * 32;
    const int tid = threadIdx.x;
    const int p   = tid & 31;
    const int c   = tid >> 5;

    __shared__ float kvs[64 * 72];
    for (int i = tid; i < 64 * 72; i += 256) kvs[i] = kvb[(size_t)b * 64 * 72 + i];
    __syncthreads();

    const int n = n0 + p;
    const size_t orow = ((size_t)b * NPIX + n) * 512;

#pragma unroll
    for (int gi = 0; gi < 8; ++gi) {
        const int g = c * 8 + gi;
        const float* __restrict__ src = (g < 32) ? qkv : agg;
        const float* __restrict__ base = src + ((size_t)b * 768 + 24 * (g & 31)) * NPIX + n;

        float q[8];
#pragma unroll
        for (int d = 0; d < 8; ++d) q[d] = fmaxf(0.0f, base[(size_t)d * NPIX]);

        const float* kv = &kvs[g * 72];
        float den = 1e-15f;
#pragma unroll
        for (int d = 0; d < 8; ++d) den = fmaf(q[d], kv[d * 9 + 8], den);
        float inv = 1.0f / den;
#pragma unroll
        for (int d = 0; d < 8; ++d) q[d] *= inv;

        bf16x8 vh, vm;
#pragma unroll
        for (int e = 0; e < 8; ++e) {
            float o = 0.0f;
#pragma unroll
            for (int d = 0; d < 8; ++d) o = fmaf(q[d], kv[d * 9 + e], o);
            bf16 h = (bf16)o;
            vh[e] = h;
            vm[e] = (bf16)(o - (float)h);
        }
        *(bf16x8*)(attTh + orow + g * 8) = vh;
        *(bf16x8*)(attTm + orow + g * 8) = vm;
    }
}

// ---------------------------------------------------------------------------
// proj GEMM via split-2 bf16 MFMA (3 products, ~2^-16 rel — round-6-validated)
// + fused BN. C[b][m][n] = BN( sum_k A[m][k] * att[k][n] ). M=256, K=512.
// Same structure as qkv_mfma. grid = (32, 2, 8); block = 256
// ---------------------------------------------------------------------------
__global__ __launch_bounds__(256, 2) void proj_mfma(
    const float* __restrict__ A,     // [256][512] w_proj
    const bf16* __restrict__ Bh,     // [8][NPIX][512]
    const bf16* __restrict__ Bm,
    float* __restrict__ C,           // [8][256][NPIX]
    const float* __restrict__ bn_g, const float* __restrict__ bn_b,
    const float* __restrict__ bn_m, const float* __restrict__ bn_v)
{
    __shared__ bf16 As[2][128][40];

    const int tid  = threadIdx.x;
    const int lane = tid & 63;
    const int wv   = tid >> 6;
    const int col  = lane & 15;
    const int quad = lane >> 4;
    const int wm   = (wv >> 1) * 64;
    const int wn   = (wv & 1) * 64;
    const int n0   = blockIdx.x * 128;
    const int m0   = blockIdx.y * 128;
    const int b    = blockIdx.z;

    const int arow = tid >> 1;
    const int akc  = (tid & 1) * 16;

    const size_t boff = ((size_t)b * NPIX + n0 + wn) * 512;

    f32x4 acc[4][4] = {};

    float av[16];
    {
        const float* ap = A + (size_t)(m0 + arow) * 512 + akc;
        *(float4*)&av[0]  = *(const float4*)(ap);
        *(float4*)&av[4]  = *(const float4*)(ap + 4);
        *(float4*)&av[8]  = *(const float4*)(ap + 8);
        *(float4*)&av[12] = *(const float4*)(ap + 12);
    }

    for (int k0 = 0; k0 < 512; k0 += 32) {
        __syncthreads();

#pragma unroll
        for (int c = 0; c < 4; ++c) {
            bf16x4 vh, vm;
#pragma unroll
            for (int j = 0; j < 4; ++j) {
                float val = av[c * 4 + j];
                bf16 h = (bf16)val;
                vh[j] = h; vm[j] = (bf16)(val - (float)h);
            }
            *(bf16x4*)&As[0][arow][akc + c * 4] = vh;
            *(bf16x4*)&As[1][arow][akc + c * 4] = vm;
        }

        if (k0 + 32 < 512) {
            const float* ap = A + (size_t)(m0 + arow) * 512 + k0 + 32 + akc;
            *(float4*)&av[0]  = *(const float4*)(ap);
            *(float4*)&av[4]  = *(const float4*)(ap + 4);
            *(float4*)&av[8]  = *(const float4*)(ap + 8);
            *(float4*)&av[12] = *(const float4*)(ap + 12);
        }

        __syncthreads();

        bf16x8 bh[4], bm2[4];
#pragma unroll
        for (int t = 0; t < 4; ++t) {
            const size_t brow = boff + (size_t)(t * 16 + col) * 512 + k0 + quad * 8;
            bh[t]  = *(const bf16x8*)(Bh + brow);
            bm2[t] = *(const bf16x8*)(Bm + brow);
        }
        bf16x8 af[4][2];
#pragma unroll
        for (int s = 0; s < 4; ++s) {
            af[s][0] = *(const bf16x8*)&As[0][wm + s * 16 + col][quad * 8];
            af[s][1] = *(const bf16x8*)&As[1][wm + s * 16 + col][quad * 8];
        }

        // small-magnitude products first
#pragma unroll
        for (int t = 0; t < 4; ++t)
#pragma unroll
            for (int s = 0; s < 4; ++s)
                acc[s][t] = __builtin_amdgcn_mfma_f32_16x16x32_bf16(af[s][1], bh[t], acc[s][t], 0, 0, 0);
#pragma unroll
        for (int t = 0; t < 4; ++t)
#pragma unroll
            for (int s = 0; s < 4; ++s)
                acc[s][t] = __builtin_amdgcn_mfma_f32_16x16x32_bf16(af[s][0], bm2[t], acc[s][t], 0, 0, 0);
#pragma unroll
        for (int t = 0; t < 4; ++t)
#pragma unroll
            for (int s = 0; s < 4; ++s)
                acc[s][t] = __builtin_amdgcn_mfma_f32_16x16x32_bf16(af[s][0], bh[t], acc[s][t], 0, 0, 0);
    }

    float* __restrict__ Cp = C + (size_t)b * 256 * NPIX;
#pragma unroll
    for (int s = 0; s < 4; ++s) {
#pragma unroll
        for (int r = 0; r < 4; ++r) {
            const int m = m0 + wm + s * 16 + quad * 4 + r;
            const float sc  = (1.0f / sqrtf(bn_v[m] + 1e-5f)) * bn_g[m];
            const float off = bn_b[m] - bn_m[m] * sc;
#pragma unroll
            for (int t = 0; t < 4; ++t) {
                const int n = n0 + wn + t * 16 + col;
                Cp[(size_t)m * NPIX + n] = acc[s][t][r] * sc + off;
            }
        }
    }
}

// ---------------------------------------------------------------------------
extern "C" void kernel_launch(void* const* d_in, const int* in_sizes, int n_in,
                              void* d_out, int out_size, void* d_ws, size_t ws_size,
                              hipStream_t stream) {
    const float* x      = (const float*)d_in[0];
    const float* w_qkv  = (const float*)d_in[1];
    const float* w_dw   = (const float*)d_in[2];
    const float* w_pw   = (const float*)d_in[3];
    const float* w_proj = (const float*)d_in[4];
    const float* bn_g   = (const float*)d_in[5];
    const float* bn_b   = (const float*)d_in[6];
    const float* bn_m   = (const float*)d_in[7];
    const float* bn_v   = (const float*)d_in[8];
    float* out = (float*)d_out;

    // ws: qkv 96 MiB + agg 96 MiB + region3 64 MiB = 256 MiB.
    // region3 timeline: xT split planes (48 MiB) for split_x/qkv_mfma, then
    // (xT dead after qkv_mfma) attT h+m planes (2 x 32 MiB) for attn->proj.
    // kvb (147 KB) lives in d_out; proj_mfma overwrites all of d_out last.
    char* ws = (char*)d_ws;
    float* qkv  = (float*)ws;                        // 100663296 B
    float* agg  = (float*)(ws + 100663296ull);       // 100663296 B
    char*  r3   = ws + 201326592ull;                 // 67108864 B
    bf16*  xTh  = (bf16*)r3;                         // 16777216 B
    bf16*  xTm  = (bf16*)(r3 + 16777216ull);         // 16777216 B
    bf16*  xTl  = (bf16*)(r3 + 33554432ull);         // 16777216 B
    bf16*  attTh = (bf16*)r3;                        // 33554432 B
    bf16*  attTm = (bf16*)(r3 + 33554432ull);        // 33554432 B
    float* kvb  = (float*)d_out;

    // 0) split + transpose x into 3 bf16 planes (h+m+l == x exactly)
    split_x<<<dim3(16, 8, 8), dim3(256), 0, stream>>>(x, xTh, xTm, xTl);

    // 1) qkv = w_qkv @ x  (split-3 MFMA, fp32-accurate)
    qkv_mfma<<<dim3(32, 6, 8), dim3(256), 0, stream>>>(w_qkv, xTh, xTm, xTl, qkv);

    // 2) agg = grouped-pw( depthwise-5x5( qkv ) )
    dwpw<<<dim3(4, 4, 8 * 96), dim3(256), 0, stream>>>(qkv, w_dw, w_pw, agg);

    // 3) kv reduction per (g, b)
    kv_reduce<<<dim3(64, 8), dim3(256), 0, stream>>>(qkv, agg, kvb);

    // 4) attention -> transposed split-2 bf16 attT (xT region now dead)
    attn_fused<<<dim3(128, 8), dim3(256), 0, stream>>>(qkv, agg, kvb, attTh, attTm);

    // 5) out = BN( w_proj @ att )  (split-2 MFMA; overwrites all of d_out)
    proj_mfma<<<dim3(32, 2, 8), dim3(256), 0, stream>>>(
        w_proj, attTh, attTm, out, bn_g, bn_b, bn_m, bn_v);
}

// Round 10
// 430.267 us; speedup vs baseline: 5.8812x; 1.0975x over previous
//
#include <hip/hip_runtime.h>

typedef __bf16 bf16;
typedef __bf16 bf16x4 __attribute__((ext_vector_type(4)));
typedef __bf16 bf16x8 __attribute__((ext_vector_type(8)));
typedef float f32x4 __attribute__((ext_vector_type(4)));

#define NPIX 4096   // 64*64

// ---------------------------------------------------------------------------
// split_x: x[b][k][pix] fp32 -> 3 bf16 planes xT[b][pix][k] (h+m+l == x exact).
// grid = (16, 8, 8); block = 256
// ---------------------------------------------------------------------------
__global__ __launch_bounds__(256) void split_x(
    const float* __restrict__ x,   // [8][256][NPIX]
    bf16* __restrict__ xTh, bf16* __restrict__ xTm, bf16* __restrict__ xTl)
{
    const int pix = blockIdx.x * 256 + threadIdx.x;
    const int k0  = blockIdx.y * 32;
    const int b   = blockIdx.z;

    const float* __restrict__ src = x + ((size_t)b * 256 + k0) * NPIX + pix;
    float v[32];
#pragma unroll
    for (int kk = 0; kk < 32; ++kk) v[kk] = src[(size_t)kk * NPIX];

    const size_t drow = ((size_t)b * NPIX + pix) * 256 + k0;
#pragma unroll
    for (int c = 0; c < 4; ++c) {
        bf16x8 vh, vm, vl;
#pragma unroll
        for (int j = 0; j < 8; ++j) {
            float val = v[c * 8 + j];
            bf16 h = (bf16)val; float r  = val - (float)h;
            bf16 m = (bf16)r;   float r2 = r - (float)m;
            vh[j] = h; vm[j] = m; vl[j] = (bf16)r2;
        }
        *(bf16x8*)(xTh + drow + c * 8) = vh;
        *(bf16x8*)(xTm + drow + c * 8) = vm;
        *(bf16x8*)(xTl + drow + c * 8) = vl;
    }
}

// ---------------------------------------------------------------------------
// qkv GEMM via split-3 bf16 MFMA (6 products == fp32-accurate). Unchanged.
// grid = (32, 6, 8); block = 256
// ---------------------------------------------------------------------------
__global__ __launch_bounds__(256, 2) void qkv_mfma(
    const float* __restrict__ A,     // [768][256]
    const bf16* __restrict__ xTh,    // [8][NPIX][256]
    const bf16* __restrict__ xTm,
    const bf16* __restrict__ xTl,
    float* __restrict__ C)           // [8][768][NPIX]
{
    __shared__ bf16 As[3][128][40];

    const int tid  = threadIdx.x;
    const int lane = tid & 63;
    const int wv   = tid >> 6;
    const int col  = lane & 15;
    const int quad = lane >> 4;
    const int wm   = (wv >> 1) * 64;
    const int wn   = (wv & 1) * 64;
    const int n0   = blockIdx.x * 128;
    const int m0   = blockIdx.y * 128;
    const int b    = blockIdx.z;

    const int arow = tid >> 1;
    const int akc  = (tid & 1) * 16;

    const size_t xoff = ((size_t)b * NPIX + n0 + wn) * 256;

    f32x4 acc[4][4] = {};

    float av[16];
    {
        const float* ap = A + (size_t)(m0 + arow) * 256 + akc;
        *(float4*)&av[0]  = *(const float4*)(ap);
        *(float4*)&av[4]  = *(const float4*)(ap + 4);
        *(float4*)&av[8]  = *(const float4*)(ap + 8);
        *(float4*)&av[12] = *(const float4*)(ap + 12);
    }

    for (int k0 = 0; k0 < 256; k0 += 32) {
        __syncthreads();

#pragma unroll
        for (int c = 0; c < 4; ++c) {
            bf16x4 vh, vm, vl;
#pragma unroll
            for (int j = 0; j < 4; ++j) {
                float val = av[c * 4 + j];
                bf16 h = (bf16)val; float r  = val - (float)h;
                bf16 m = (bf16)r;   float r2 = r - (float)m;
                vh[j] = h; vm[j] = m; vl[j] = (bf16)r2;
            }
            *(bf16x4*)&As[0][arow][akc + c * 4] = vh;
            *(bf16x4*)&As[1][arow][akc + c * 4] = vm;
            *(bf16x4*)&As[2][arow][akc + c * 4] = vl;
        }

        if (k0 + 32 < 256) {
            const float* ap = A + (size_t)(m0 + arow) * 256 + k0 + 32 + akc;
            *(float4*)&av[0]  = *(const float4*)(ap);
            *(float4*)&av[4]  = *(const float4*)(ap + 4);
            *(float4*)&av[8]  = *(const float4*)(ap + 8);
            *(float4*)&av[12] = *(const float4*)(ap + 12);
        }

        __syncthreads();

        bf16x8 bh[4], bm[4], bl[4];
#pragma unroll
        for (int t = 0; t < 4; ++t) {
            const size_t brow = xoff + (size_t)(t * 16 + col) * 256 + k0 + quad * 8;
            bh[t] = *(const bf16x8*)(xTh + brow);
            bm[t] = *(const bf16x8*)(xTm + brow);
            bl[t] = *(const bf16x8*)(xTl + brow);
        }
        bf16x8 af[4][3];
#pragma unroll
        for (int s = 0; s < 4; ++s)
#pragma unroll
            for (int p = 0; p < 3; ++p)
                af[s][p] = *(const bf16x8*)&As[p][wm + s * 16 + col][quad * 8];

#pragma unroll
        for (int t = 0; t < 4; ++t)
#pragma unroll
            for (int s = 0; s < 4; ++s)
                acc[s][t] = __builtin_amdgcn_mfma_f32_16x16x32_bf16(af[s][2], bh[t], acc[s][t], 0, 0, 0);
#pragma unroll
        for (int t = 0; t < 4; ++t)
#pragma unroll
            for (int s = 0; s < 4; ++s)
                acc[s][t] = __builtin_amdgcn_mfma_f32_16x16x32_bf16(af[s][0], bl[t], acc[s][t], 0, 0, 0);
#pragma unroll
        for (int t = 0; t < 4; ++t)
#pragma unroll
            for (int s = 0; s < 4; ++s)
                acc[s][t] = __builtin_amdgcn_mfma_f32_16x16x32_bf16(af[s][1], bm[t], acc[s][t], 0, 0, 0);
#pragma unroll
        for (int t = 0; t < 4; ++t)
#pragma unroll
            for (int s = 0; s < 4; ++s)
                acc[s][t] = __builtin_amdgcn_mfma_f32_16x16x32_bf16(af[s][1], bh[t], acc[s][t], 0, 0, 0);
#pragma unroll
        for (int t = 0; t < 4; ++t)
#pragma unroll
            for (int s = 0; s < 4; ++s)
                acc[s][t] = __builtin_amdgcn_mfma_f32_16x16x32_bf16(af[s][0], bm[t], acc[s][t], 0, 0, 0);
#pragma unroll
        for (int t = 0; t < 4; ++t)
#pragma unroll
            for (int s = 0; s < 4; ++s)
                acc[s][t] = __builtin_amdgcn_mfma_f32_16x16x32_bf16(af[s][0], bh[t], acc[s][t], 0, 0, 0);
    }

    float* __restrict__ Cp = C + (size_t)b * 768 * NPIX;
#pragma unroll
    for (int s = 0; s < 4; ++s)
#pragma unroll
        for (int t = 0; t < 4; ++t)
#pragma unroll
            for (int r = 0; r < 4; ++r) {
                const int m = m0 + wm + s * 16 + quad * 4 + r;
                const int n = n0 + wn + t * 16 + col;
                Cp[(size_t)m * NPIX + n] = acc[s][t][r];
            }
}

// ---------------------------------------------------------------------------
// Fused depthwise 5x5 (pad 2) + grouped pointwise 8->8 — LDS-traffic rewrite.
// Tile: full image width 64 x 16 rows per block; 8-channel group.
// Threads: 16 tx (4 px each) x 16 ty (row). LDS rows padded: data at col 4.
// Weights read via block-uniform global indices -> scalar s_loads (no LDS).
// grid = (4, 96, 8); block = 256
// ---------------------------------------------------------------------------
__global__ __launch_bounds__(256) void dwpw(
    const float* __restrict__ qkv,   // [batch][768][NPIX]
    const float* __restrict__ w_dw,  // [768][25]
    const float* __restrict__ w_pw,  // [768][8]
    float* __restrict__ agg)         // [batch][768][NPIX]
{
    __shared__ float sm[8][20][72];  // data cols 4..67; halo cols 2,3,68,69

    const int tid = threadIdx.x;
    const int y0  = blockIdx.x * 16;
    const int p   = blockIdx.y;
    const int b   = blockIdx.z;

    const float* __restrict__ src = qkv + ((size_t)b * 768 + 8 * p) * NPIX;

    // stage: 8 ch x 20 rows x 16 float4 = 2560 vector loads
#pragma unroll
    for (int it = 0; it < 10; ++it) {
        int idx = tid + it * 256;
        int c  = idx / 320;
        int r  = idx % 320;
        int sy = r >> 4;
        int x4 = (r & 15) * 4;
        int gy = y0 + sy - 2;
        float4 v = {0.f, 0.f, 0.f, 0.f};
        if ((unsigned)gy < 64u)
            v = *(const float4*)(src + (size_t)c * NPIX + gy * 64 + x4);
        *(float4*)&sm[c][sy][4 + x4] = v;
    }
    // x-halo zero: 8 ch x 20 rows x {2,3,68,69}
    if (tid < 160) {
        int c = tid / 20, sy = tid % 20;
        sm[c][sy][2] = 0.f; sm[c][sy][3] = 0.f;
        sm[c][sy][68] = 0.f; sm[c][sy][69] = 0.f;
    }
    __syncthreads();

    const int ty = tid >> 4;          // row 0..15
    const int x0 = (tid & 15) * 4;    // first pixel of 4

    // depthwise: d[c][j] for 4 pixels
    float d[8][4];
#pragma unroll
    for (int c = 0; c < 8; ++c) {
        float a0 = 0.f, a1 = 0.f, a2 = 0.f, a3 = 0.f;
        const float* __restrict__ wc = w_dw + (size_t)(8 * p + c) * 25;
#pragma unroll
        for (int ky = 0; ky < 5; ++ky) {
            float r[12];
            *(float4*)&r[0] = *(const float4*)&sm[c][ty + ky][x0];
            *(float4*)&r[4] = *(const float4*)&sm[c][ty + ky][x0 + 4];
            *(float4*)&r[8] = *(const float4*)&sm[c][ty + ky][x0 + 8];
#pragma unroll
            for (int kx = 0; kx < 5; ++kx) {
                const float wv = wc[ky * 5 + kx];   // uniform -> s_load
                a0 = fmaf(wv, r[2 + 0 + kx], a0);
                a1 = fmaf(wv, r[2 + 1 + kx], a1);
                a2 = fmaf(wv, r[2 + 2 + kx], a2);
                a3 = fmaf(wv, r[2 + 3 + kx], a3);
            }
        }
        d[c][0] = a0; d[c][1] = a1; d[c][2] = a2; d[c][3] = a3;
    }

    // pointwise 8->8 + store float4
    float* __restrict__ dst = agg + ((size_t)b * 768 + 8 * p) * NPIX + (y0 + ty) * 64 + x0;
#pragma unroll
    for (int o = 0; o < 8; ++o) {
        const float* __restrict__ wo = w_pw + (size_t)(8 * p + o) * 8;  // uniform
        float4 s = {0.f, 0.f, 0.f, 0.f};
#pragma unroll
        for (int i = 0; i < 8; ++i) {
            const float wv = wo[i];
            s.x = fmaf(wv, d[i][0], s.x);
            s.y = fmaf(wv, d[i][1], s.y);
            s.z = fmaf(wv, d[i][2], s.z);
            s.w = fmaf(wv, d[i][3], s.w);
        }
        *(float4*)(dst + (size_t)o * NPIX) = s;
    }
}

// ---------------------------------------------------------------------------
// kv[b][g][d][e] = sum_n relu(k[n][d]) * v'[n][e]   (v'[:,8] = 1). Unchanged.
// grid = (64, batch); block = 256
// ---------------------------------------------------------------------------
__global__ __launch_bounds__(256) void kv_reduce(
    const float* __restrict__ qkv, const float* __restrict__ agg,
    float* __restrict__ kvb)      // [batch][64][72]
{
    const int g = blockIdx.x, b = blockIdx.y;
    const float* __restrict__ src = (g < 32) ? qkv : agg;
    const float* __restrict__ base = src + ((size_t)b * 768 + 24 * (g & 31)) * NPIX;

    float acc[72];
#pragma unroll
    for (int i = 0; i < 72; ++i) acc[i] = 0.0f;

    for (int i4 = threadIdx.x; i4 < NPIX / 4; i4 += 256) {
        float4 kf[8], vf[8];
#pragma unroll
        for (int d = 0; d < 8; ++d) {
            float4 t = ((const float4*)(base + (size_t)(8 + d) * NPIX))[i4];
            kf[d].x = fmaxf(0.0f, t.x); kf[d].y = fmaxf(0.0f, t.y);
            kf[d].z = fmaxf(0.0f, t.z); kf[d].w = fmaxf(0.0f, t.w);
        }
#pragma unroll
        for (int e = 0; e < 8; ++e)
            vf[e] = ((const float4*)(base + (size_t)(16 + e) * NPIX))[i4];
#pragma unroll
        for (int d = 0; d < 8; ++d) {
#pragma unroll
            for (int e = 0; e < 8; ++e)
                acc[d * 9 + e] += kf[d].x * vf[e].x + kf[d].y * vf[e].y +
                                  kf[d].z * vf[e].z + kf[d].w * vf[e].w;
            acc[d * 9 + 8] += kf[d].x + kf[d].y + kf[d].z + kf[d].w;
        }
    }

    const int lane = threadIdx.x & 63;
    const int wv   = threadIdx.x >> 6;
#pragma unroll
    for (int i = 0; i < 72; ++i) {
        float v = acc[i];
        v += __shfl_xor(v, 32, 64);
        v += __shfl_xor(v, 16, 64);
        v += __shfl_xor(v, 8, 64);
        v += __shfl_xor(v, 4, 64);
        v += __shfl_xor(v, 2, 64);
        v += __shfl_xor(v, 1, 64);
        acc[i] = v;
    }
    __shared__ float red[4][72];
    if (lane == 0) {
#pragma unroll
        for (int i = 0; i < 72; ++i) red[wv][i] = acc[i];
    }
    __syncthreads();
    if (threadIdx.x < 72)
        kvb[((size_t)b * 64 + g) * 72 + threadIdx.x] =
            red[0][threadIdx.x] + red[1][threadIdx.x] +
            red[2][threadIdx.x] + red[3][threadIdx.x];
}

// ---------------------------------------------------------------------------
// attn_fused: normalized attention -> transposed split-2 bf16 attT planes.
// grid = (128, 8); block = 256. Unchanged.
// ---------------------------------------------------------------------------
__global__ __launch_bounds__(256) void attn_fused(
    const float* __restrict__ qkv, const float* __restrict__ agg,
    const float* __restrict__ kvb,   // [batch][64][72]
    bf16* __restrict__ attTh, bf16* __restrict__ attTm)  // [8][NPIX][512]
{
    const int b   = blockIdx.y;
    const int n0  = blockIdx.x * 32;
    const int tid = threadIdx.x;
    const int p   = tid & 31;
    const int c   = tid >> 5;

    __shared__ float kvs[64 * 72];
    for (int i = tid; i < 64 * 72; i += 256) kvs[i] = kvb[(size_t)b * 64 * 72 + i];
    __syncthreads();

    const int n = n0 + p;
    const size_t orow = ((size_t)b * NPIX + n) * 512;

#pragma unroll
    for (int gi = 0; gi < 8; ++gi) {
        const int g = c * 8 + gi;
        const float* __restrict__ src = (g < 32) ? qkv : agg;
        const float* __restrict__ base = src + ((size_t)b * 768 + 24 * (g & 31)) * NPIX + n;

        float q[8];
#pragma unroll
        for (int d = 0; d < 8; ++d) q[d] = fmaxf(0.0f, base[(size_t)d * NPIX]);

        const float* kv = &kvs[g * 72];
        float den = 1e-15f;
#pragma unroll
        for (int d = 0; d < 8; ++d) den = fmaf(q[d], kv[d * 9 + 8], den);
        float inv = 1.0f / den;
#pragma unroll
        for (int d = 0; d < 8; ++d) q[d] *= inv;

        bf16x8 vh, vm;
#pragma unroll
        for (int e = 0; e < 8; ++e) {
            float o = 0.0f;
#pragma unroll
            for (int d = 0; d < 8; ++d) o = fmaf(q[d], kv[d * 9 + e], o);
            bf16 h = (bf16)o;
            vh[e] = h;
            vm[e] = (bf16)(o - (float)h);
        }
        *(bf16x8*)(attTh + orow + g * 8) = vh;
        *(bf16x8*)(attTm + orow + g * 8) = vm;
    }
}

// ---------------------------------------------------------------------------
// proj GEMM via split-2 bf16 MFMA + fused BN. Unchanged.
// grid = (32, 2, 8); block = 256
// ---------------------------------------------------------------------------
__global__ __launch_bounds__(256, 2) void proj_mfma(
    const float* __restrict__ A,     // [256][512] w_proj
    const bf16* __restrict__ Bh,     // [8][NPIX][512]
    const bf16* __restrict__ Bm,
    float* __restrict__ C,           // [8][256][NPIX]
    const float* __restrict__ bn_g, const float* __restrict__ bn_b,
    const float* __restrict__ bn_m, const float* __restrict__ bn_v)
{
    __shared__ bf16 As[2][128][40];

    const int tid  = threadIdx.x;
    const int lane = tid & 63;
    const int wv   = tid >> 6;
    const int col  = lane & 15;
    const int quad = lane >> 4;
    const int wm   = (wv >> 1) * 64;
    const int wn   = (wv & 1) * 64;
    const int n0   = blockIdx.x * 128;
    const int m0   = blockIdx.y * 128;
    const int b    = blockIdx.z;

    const int arow = tid >> 1;
    const int akc  = (tid & 1) * 16;

    const size_t boff = ((size_t)b * NPIX + n0 + wn) * 512;

    f32x4 acc[4][4] = {};

    float av[16];
    {
        const float* ap = A + (size_t)(m0 + arow) * 512 + akc;
        *(float4*)&av[0]  = *(const float4*)(ap);
        *(float4*)&av[4]  = *(const float4*)(ap + 4);
        *(float4*)&av[8]  = *(const float4*)(ap + 8);
        *(float4*)&av[12] = *(const float4*)(ap + 12);
    }

    for (int k0 = 0; k0 < 512; k0 += 32) {
        __syncthreads();

#pragma unroll
        for (int c = 0; c < 4; ++c) {
            bf16x4 vh, vm;
#pragma unroll
            for (int j = 0; j < 4; ++j) {
                float val = av[c * 4 + j];
                bf16 h = (bf16)val;
                vh[j] = h; vm[j] = (bf16)(val - (float)h);
            }
            *(bf16x4*)&As[0][arow][akc + c * 4] = vh;
            *(bf16x4*)&As[1][arow][akc + c * 4] = vm;
        }

        if (k0 + 32 < 512) {
            const float* ap = A + (size_t)(m0 + arow) * 512 + k0 + 32 + akc;
            *(float4*)&av[0]  = *(const float4*)(ap);
            *(float4*)&av[4]  = *(const float4*)(ap + 4);
            *(float4*)&av[8]  = *(const float4*)(ap + 8);
            *(float4*)&av[12] = *(const float4*)(ap + 12);
        }

        __syncthreads();

        bf16x8 bh[4], bm2[4];
#pragma unroll
        for (int t = 0; t < 4; ++t) {
            const size_t brow = boff + (size_t)(t * 16 + col) * 512 + k0 + quad * 8;
            bh[t]  = *(const bf16x8*)(Bh + brow);
            bm2[t] = *(const bf16x8*)(Bm + brow);
        }
        bf16x8 af[4][2];
#pragma unroll
        for (int s = 0; s < 4; ++s) {
            af[s][0] = *(const bf16x8*)&As[0][wm + s * 16 + col][quad * 8];
            af[s][1] = *(const bf16x8*)&As[1][wm + s * 16 + col][quad * 8];
        }

#pragma unroll
        for (int t = 0; t < 4; ++t)
#pragma unroll
            for (int s = 0; s < 4; ++s)
                acc[s][t] = __builtin_amdgcn_mfma_f32_16x16x32_bf16(af[s][1], bh[t], acc[s][t], 0, 0, 0);
#pragma unroll
        for (int t = 0; t < 4; ++t)
#pragma unroll
            for (int s = 0; s < 4; ++s)
                acc[s][t] = __builtin_amdgcn_mfma_f32_16x16x32_bf16(af[s][0], bm2[t], acc[s][t], 0, 0, 0);
#pragma unroll
        for (int t = 0; t < 4; ++t)
#pragma unroll
            for (int s = 0; s < 4; ++s)
                acc[s][t] = __builtin_amdgcn_mfma_f32_16x16x32_bf16(af[s][0], bh[t], acc[s][t], 0, 0, 0);
    }

    float* __restrict__ Cp = C + (size_t)b * 256 * NPIX;
#pragma unroll
    for (int s = 0; s < 4; ++s) {
#pragma unroll
        for (int r = 0; r < 4; ++r) {
            const int m = m0 + wm + s * 16 + quad * 4 + r;
            const float sc  = (1.0f / sqrtf(bn_v[m] + 1e-5f)) * bn_g[m];
            const float off = bn_b[m] - bn_m[m] * sc;
#pragma unroll
            for (int t = 0; t < 4; ++t) {
                const int n = n0 + wn + t * 16 + col;
                Cp[(size_t)m * NPIX + n] = acc[s][t][r] * sc + off;
            }
        }
    }
}

// ---------------------------------------------------------------------------
extern "C" void kernel_launch(void* const* d_in, const int* in_sizes, int n_in,
                              void* d_out, int out_size, void* d_ws, size_t ws_size,
                              hipStream_t stream) {
    const float* x      = (const float*)d_in[0];
    const float* w_qkv  = (const float*)d_in[1];
    const float* w_dw   = (const float*)d_in[2];
    const float* w_pw   = (const float*)d_in[3];
    const float* w_proj = (const float*)d_in[4];
    const float* bn_g   = (const float*)d_in[5];
    const float* bn_b   = (const float*)d_in[6];
    const float* bn_m   = (const float*)d_in[7];
    const float* bn_v   = (const float*)d_in[8];
    float* out = (float*)d_out;

    // ws: qkv 96 MiB + agg 96 MiB + region3 64 MiB = 256 MiB.
    // region3: xT planes (48 MiB) until qkv_mfma, then attT h+m (2 x 32 MiB).
    // kvb (147 KB) lives in d_out; proj_mfma overwrites all of d_out last.
    char* ws = (char*)d_ws;
    float* qkv  = (float*)ws;                        // 100663296 B
    float* agg  = (float*)(ws + 100663296ull);       // 100663296 B
    char*  r3   = ws + 201326592ull;                 // 67108864 B
    bf16*  xTh  = (bf16*)r3;                         // 16777216 B
    bf16*  xTm  = (bf16*)(r3 + 16777216ull);         // 16777216 B
    bf16*  xTl  = (bf16*)(r3 + 33554432ull);         // 16777216 B
    bf16*  attTh = (bf16*)r3;                        // 33554432 B
    bf16*  attTm = (bf16*)(r3 + 33554432ull);        // 33554432 B
    float* kvb  = (float*)d_out;

    // 0) split + transpose x into 3 bf16 planes (h+m+l == x exactly)
    split_x<<<dim3(16, 8, 8), dim3(256), 0, stream>>>(x, xTh, xTm, xTl);

    // 1) qkv = w_qkv @ x  (split-3 MFMA, fp32-accurate)
    qkv_mfma<<<dim3(32, 6, 8), dim3(256), 0, stream>>>(w_qkv, xTh, xTm, xTl, qkv);

    // 2) agg = grouped-pw( depthwise-5x5( qkv ) )  (64x16 tiles, b128 LDS)
    dwpw<<<dim3(4, 96, 8), dim3(256), 0, stream>>>(qkv, w_dw, w_pw, agg);

    // 3) kv reduction per (g, b)
    kv_reduce<<<dim3(64, 8), dim3(256), 0, stream>>>(qkv, agg, kvb);

    // 4) attention -> transposed split-2 bf16 attT (xT region now dead)
    attn_fused<<<dim3(128, 8), dim3(256), 0, stream>>>(qkv, agg, kvb, attTh, attTm);

    // 5) out = BN( w_proj @ att )  (split-2 MFMA; overwrites all of d_out)
    proj_mfma<<<dim3(32, 2, 8), dim3(256), 0, stream>>>(
        w_proj, attTh, attTm, out, bn_g, bn_b, bn_m, bn_v);
}